// Round 7
// baseline (1076.285 us; speedup 1.0000x reference)
//
#include <hip/hip_runtime.h>
#include <hip/hip_bf16.h>
#include <math.h>

// Differential causal self-attention. ALL I/O float32; internal bf16 MFMA.
// FAST PATH (ws_size >= 40MB): batch-merged launches, 6 dispatches.
//   ws: [0,16M) xb (x as bf16; reused as attn-out after QKV consumes it)
//       [16M,24M) Wq,Wk,Wv,Wproj as bf16 (2MB each)
//       [24M,40M) vt = V transposed per batch: vt[b][dim 0..1023][t 0..2047]
//   d_out: [0,16M) q bf16, [16M,32M) k bf16 (dead before proj writes f32)
// Attention: FIXED-max softmax (rmsnorm => |S|<=8(1+eps), m=9 const).
// All attn LDS tiles: pitch 64 + XOR chunk swizzle (chunk ^ (row&7), 16B
// granularity) -> conflict-free b128, total 40960B = 4 blocks/CU.
// [Round-6 bug was ps pitch 40 < tile width 64 -> row overlap. Fixed.]
// FALLBACK (small ws): round-4 proven per-batch pipeline, zero ws usage.

typedef __bf16 bf16_t;
typedef __bf16 bf16x8 __attribute__((ext_vector_type(8)));
typedef __bf16 bf16x4 __attribute__((ext_vector_type(4)));
typedef float  f32x4  __attribute__((ext_vector_type(4)));

#define T_SEQ 2048
#define C_EMB 1024
static constexpr float LAMBDA_INIT = 0.6192834728526787f;   // 0.8 - 0.6*exp(-1.2)
static constexpr float ONE_MINUS_LI = 0.3807165271473213f;
static constexpr float RMS_EPS = 1.1920928955078125e-07f;
static constexpr float LN_EPS = 1e-5f;
static constexpr float M_FIX = 9.0f;    // fixed softmax max (|S| <= ~8.05)

__device__ __forceinline__ f32x4 mfma16(bf16x8 a, bf16x8 b, f32x4 c) {
  return __builtin_amdgcn_mfma_f32_16x16x32_bf16(a, b, c, 0, 0, 0);
}
__device__ __forceinline__ float declamp(float v, float lim) {
  return fminf(fmaxf(v, -lim), lim);   // IEEE min/max: NaN firewall too
}

// ==================== FAST PATH ====================

// ---- one-shot f32 -> bf16 convert: x (8M) + 4 weights (1M each) ----
__global__ __launch_bounds__(256) void cvt_all(
    const float* __restrict__ x,  const float* __restrict__ Wq,
    const float* __restrict__ Wk, const float* __restrict__ Wv,
    const float* __restrict__ Wp,
    bf16_t* __restrict__ xb,  bf16_t* __restrict__ wqb, bf16_t* __restrict__ wkb,
    bf16_t* __restrict__ wvb, bf16_t* __restrict__ wpb)
{
  size_t i4 = ((size_t)blockIdx.x * 256 + threadIdx.x) * 4;
  const float* s; bf16_t* d; size_t off;
  if      (i4 <  8388608) { s = x;  d = xb;  off = i4; }
  else if (i4 <  9437184) { s = Wq; d = wqb; off = i4 - 8388608; }
  else if (i4 < 10485760) { s = Wk; d = wkb; off = i4 - 9437184; }
  else if (i4 < 11534336) { s = Wv; d = wvb; off = i4 - 10485760; }
  else                    { s = Wp; d = wpb; off = i4 - 11534336; }
  f32x4 v = *(const f32x4*)(s + off);
  bf16x4 bv;
#pragma unroll
  for (int j = 0; j < 4; ++j) bv[j] = (bf16_t)v[j];
  *(bf16x4*)(d + off) = bv;
}

// ---- shared GEMM mainloop: acc = A(128 rows) @ W(128 rows)^T over K=1024 ----
__device__ __forceinline__ void gemm_core(
    const bf16_t* __restrict__ A, const bf16_t* __restrict__ W,
    bf16_t* As, bf16_t* Bs, f32x4 acc[4][4], int m0, int n0)
{
  const int tid = threadIdx.x;
  const int lane = tid & 63, w = tid >> 6;
  const int wm = w >> 1, wn = w & 1;
  const int l15 = lane & 15, quad = lane >> 4;
  for (int k0 = 0; k0 < C_EMB; k0 += 32) {
#pragma unroll
    for (int i = 0; i < 2; ++i) {
      int c = tid + i * 256;            // 512 x 16B chunks
      int r = c >> 2, c8 = (c & 3) * 8;
      *(bf16x8*)&As[r * 40 + c8] = *(const bf16x8*)&A[(size_t)(m0 + r) * C_EMB + k0 + c8];
      *(bf16x8*)&Bs[r * 40 + c8] = *(const bf16x8*)&W[(size_t)(n0 + r) * C_EMB + k0 + c8];
    }
    __syncthreads();
    bf16x8 af[4], bfr[4];
#pragma unroll
    for (int i = 0; i < 4; ++i)
      af[i] = *(const bf16x8*)&As[(wm * 64 + i * 16 + l15) * 40 + quad * 8];
#pragma unroll
    for (int j = 0; j < 4; ++j)
      bfr[j] = *(const bf16x8*)&Bs[(wn * 64 + j * 16 + l15) * 40 + quad * 8];
#pragma unroll
    for (int i = 0; i < 4; ++i)
#pragma unroll
      for (int j = 0; j < 4; ++j) acc[i][j] = mfma16(af[i], bfr[j], acc[i][j]);
    __syncthreads();
  }
}

// ---- QKV gemm over all batches (M=8192). z=0 q, z=1 k (row-major bf16),
//      z=2 v written TRANSPOSED: vt[b][col][t] (bf16x4 along t, no LDS) ----
__global__ __launch_bounds__(256) void gemm_qkv(
    const bf16_t* __restrict__ A,
    const bf16_t* __restrict__ Wqb, const bf16_t* __restrict__ Wkb, const bf16_t* __restrict__ Wvb,
    bf16_t* __restrict__ qo, bf16_t* __restrict__ ko, bf16_t* __restrict__ vt)
{
  const int z = blockIdx.z;
  const bf16_t* W = (z == 0) ? Wqb : ((z == 1) ? Wkb : Wvb);
  const int n0 = blockIdx.x * 128, m0 = blockIdx.y * 128;
  __shared__ bf16_t As[128 * 40];
  __shared__ bf16_t Bs[128 * 40];
  const int lane = threadIdx.x & 63, w = threadIdx.x >> 6;
  const int wm = w >> 1, wn = w & 1;
  const int l15 = lane & 15, quad = lane >> 4;
  const f32x4 fz = {0.f, 0.f, 0.f, 0.f};
  f32x4 acc[4][4];
#pragma unroll
  for (int i = 0; i < 4; ++i)
#pragma unroll
    for (int j = 0; j < 4; ++j) acc[i][j] = fz;
  gemm_core(A, W, As, Bs, acc, m0, n0);

  if (z < 2) {
    bf16_t* C = z ? ko : qo;
#pragma unroll
    for (int i = 0; i < 4; ++i)
#pragma unroll
      for (int j = 0; j < 4; ++j)
#pragma unroll
        for (int r = 0; r < 4; ++r) {
          int row = m0 + wm * 64 + i * 16 + quad * 4 + r;
          int col = n0 + wn * 64 + j * 16 + l15;
          C[(size_t)row * C_EMB + col] = (bf16_t)declamp(acc[i][j][r], 1e4f);
        }
  } else {
#pragma unroll
    for (int i = 0; i < 4; ++i)
#pragma unroll
      for (int j = 0; j < 4; ++j) {
        int row = m0 + wm * 64 + i * 16 + quad * 4;   // multiple of 4, same batch
        int col = n0 + wn * 64 + j * 16 + l15;
        bf16x4 pv;
#pragma unroll
        for (int r = 0; r < 4; ++r) pv[r] = (bf16_t)declamp(acc[i][j][r], 1e4f);
        size_t idx = (size_t)(row >> 11) * 2097152 + (size_t)col * 2048 + (row & 2047);
        *(bf16x4*)&vt[idx] = pv;
      }
  }
}

// ---- proj gemm: bf16 A/W -> f32 out ----
__global__ __launch_bounds__(256) void gemm_proj(
    const bf16_t* __restrict__ A, const bf16_t* __restrict__ Wpb, float* __restrict__ C)
{
  const int n0 = blockIdx.x * 128, m0 = blockIdx.y * 128;
  __shared__ bf16_t As[128 * 40];
  __shared__ bf16_t Bs[128 * 40];
  const int lane = threadIdx.x & 63, w = threadIdx.x >> 6;
  const int wm = w >> 1, wn = w & 1;
  const int l15 = lane & 15, quad = lane >> 4;
  const f32x4 fz = {0.f, 0.f, 0.f, 0.f};
  f32x4 acc[4][4];
#pragma unroll
  for (int i = 0; i < 4; ++i)
#pragma unroll
    for (int j = 0; j < 4; ++j) acc[i][j] = fz;
  gemm_core(A, Wpb, As, Bs, acc, m0, n0);
#pragma unroll
  for (int i = 0; i < 4; ++i)
#pragma unroll
    for (int j = 0; j < 4; ++j)
#pragma unroll
      for (int r = 0; r < 4; ++r) {
        int row = m0 + wm * 64 + i * 16 + quad * 4 + r;
        int col = n0 + wn * 64 + j * 16 + l15;
        C[(size_t)row * C_EMB + col] = declamp(acc[i][j][r], 1e4f);
      }
}

// ---- RMSNorm + RoPE in place, q and k in one launch (blockIdx.y) ----
__global__ __launch_bounds__(256) void rope_rms2(bf16_t* __restrict__ q, bf16_t* __restrict__ k)
{
  bf16_t* arr = blockIdx.y ? k : q;
  const float scale = blockIdx.y ? 1.0f : 0.125f;   // q gets 1/sqrt(64)
  const int tid = threadIdx.x;
  const int g = blockIdx.x * 16 + (tid >> 4);       // row*16 + sh, row in [0,8192)
  const int l16 = tid & 15;
  const int t = (g >> 4) & (T_SEQ - 1);
  bf16_t* p = arr + (size_t)g * 64 + l16 * 4;

  bf16x4 xv = *(const bf16x4*)p;
  float x[4];
#pragma unroll
  for (int j = 0; j < 4; ++j) x[j] = (float)xv[j];
  float ss = x[0]*x[0] + x[1]*x[1] + x[2]*x[2] + x[3]*x[3];
#pragma unroll
  for (int mm = 1; mm <= 8; mm <<= 1) ss += __shfl_xor(ss, mm);
  const float rn = rsqrtf(fmaxf(ss, 0.f) * (1.0f / 64.0f) + RMS_EPS);
  float nrm[4], prt[4];
#pragma unroll
  for (int j = 0; j < 4; ++j) nrm[j] = x[j] * rn;
#pragma unroll
  for (int j = 0; j < 4; ++j) prt[j] = __shfl_xor(nrm[j], 8);

  const int ib = (l16 & 7) * 4;
  const float sgn = (l16 < 8) ? 1.f : -1.f;
  bf16x4 ov;
#pragma unroll
  for (int j = 0; j < 4; ++j) {
    int i = ib + j;
    float invf = expf(-(float)i * 0.28782313662425575f);  // 10000^(-i/32)
    float ang = (float)t * invf;
    float c = cosf(ang), s = sinf(ang);
    ov[j] = (bf16_t)((nrm[j] * c + sgn * prt[j] * s) * scale);
  }
  *(bf16x4*)p = ov;
}

// ---- FIXED-MAX attention step. All tiles pitch 64, XOR chunk swizzle:
//      element (row, col=c*8+j) stored at row*64 + ((c ^ (row&7))*8 + j) ----
__device__ __forceinline__ void attn_step_fm(
    const bf16_t* __restrict__ ks, bf16_t* __restrict__ pw, const bf16_t* __restrict__ vts,
    const bf16x8* qf, float* rsum, f32x4* o,
    bool diag, int k0, int q0, int w, int l15, int quad)
{
  const int xs = l15 & 7;        // row&7 for rows ≡ l15 (mod 16)
  f32x4 sc[4];
#pragma unroll
  for (int nt = 0; nt < 4; ++nt) {
    f32x4 a = {0.f, 0.f, 0.f, 0.f};
#pragma unroll
    for (int s = 0; s < 2; ++s) {
      bf16x8 b = *(const bf16x8*)&ks[(nt * 16 + l15) * 64 + ((((s << 2) + quad) ^ xs) << 3)];
      a = mfma16(qf[s], b, a);
    }
#pragma unroll
    for (int r = 0; r < 4; ++r) a[r] = declamp(a[r], 30.f);   // NaN firewall
    sc[nt] = a;
  }
  if (diag) {
#pragma unroll
    for (int nt = 0; nt < 4; ++nt)
#pragma unroll
      for (int r = 0; r < 4; ++r) {
        int col = k0 + nt * 16 + l15;
        int row = q0 + w * 16 + quad * 4 + r;
        if (col > row) sc[nt][r] = -1e30f;
      }
  }
  // P = exp(S - M_FIX); per-lane row partial sums (reduced once in epilogue)
#pragma unroll
  for (int nt = 0; nt < 4; ++nt)
#pragma unroll
    for (int r = 0; r < 4; ++r) {
      float pv = __expf(sc[nt][r] - M_FIX);
      rsum[r] += pv;
      int row = quad * 4 + r;
      int col = nt * 16 + l15;
      pw[row * 64 + ((((col >> 3) ^ (row & 7)) << 3) | (col & 7))] = (bf16_t)pv;
    }
  // O += P(16x64) @ V(64x128)
#pragma unroll
  for (int s = 0; s < 2; ++s) {
    bf16x8 pa = *(const bf16x8*)&pw[l15 * 64 + ((((s << 2) + quad) ^ xs) << 3)];
#pragma unroll
    for (int nt2 = 0; nt2 < 8; ++nt2) {
      bf16x8 vb = *(const bf16x8*)&vts[(nt2 * 16 + l15) * 64 + ((((s << 2) + quad) ^ xs) << 3)];
      o[nt2] = mfma16(pa, vb, o[nt2]);
    }
  }
}

// ---- batch-merged diff attention; V staged from pre-transposed vt ----
// LDS = 40960B exactly -> 4 blocks/CU; launch_bounds(256,4) caps VGPR at 128.
__global__ __launch_bounds__(256, 4) void diff_attn2(
    const bf16_t* __restrict__ qp, const bf16_t* __restrict__ kp, const bf16_t* __restrict__ vtp,
    const float* __restrict__ lq1, const float* __restrict__ lk1,
    const float* __restrict__ lq2, const float* __restrict__ lk2,
    bf16_t* __restrict__ outp)
{
  const int bx = 31 - blockIdx.x;          // longest chains dispatched first
  const int b = blockIdx.y >> 3, h = blockIdx.y & 7;
  const int q0 = bx * 64;
  const int tid = threadIdx.x;
  const int lane = tid & 63, w = tid >> 6;
  const int l15 = lane & 15, quad = lane >> 4;
  const size_t bT = (size_t)b * T_SEQ;
  const bf16_t* vth = vtp + (size_t)b * 2097152 + (size_t)(h * 128) * 2048;

  __shared__ bf16_t k1s[64 * 64];          // pitch 64, XOR chunk swizzle
  __shared__ bf16_t k2s[64 * 64];
  __shared__ bf16_t vts[128 * 64];
  __shared__ bf16_t ps[4][16 * 64];

  float e1 = lq1[lane] * lk1[lane];
  float e2 = lq2[lane] * lk2[lane];
#pragma unroll
  for (int mm = 1; mm <= 32; mm <<= 1) { e1 += __shfl_xor(e1, mm); e2 += __shfl_xor(e2, mm); }
  const float lam = expf(declamp(e1, 30.f)) - expf(declamp(e2, 30.f)) + LAMBDA_INIT;

  const int sh1 = 2 * h, sh2 = 2 * h + 1;
  const int tq = q0 + w * 16 + l15;
  const bf16_t* qrow = qp + (bT + tq) * 1024;
  bf16x8 q1f[2], q2f[2];
#pragma unroll
  for (int s = 0; s < 2; ++s) {
    q1f[s] = *(const bf16x8*)&qrow[sh1 * 64 + s * 32 + quad * 8];
    q2f[s] = *(const bf16x8*)&qrow[sh2 * 64 + s * 32 + quad * 8];
  }

  const f32x4 fz = {0.f, 0.f, 0.f, 0.f};
  f32x4 o1[8], o2[8];
  float rs1[4] = {0, 0, 0, 0}, rs2[4] = {0, 0, 0, 0};
#pragma unroll
  for (int i = 0; i < 8; ++i) { o1[i] = fz; o2[i] = fz; }

  for (int kt = 0; kt <= bx; ++kt) {
    const int k0 = kt * 64;
    __syncthreads();
    // K tiles (swizzled write: chunk ^ (row&7))
#pragma unroll
    for (int i = 0; i < 2; ++i) {
      int c = tid + i * 256;
      int r = c >> 3, kc = c & 7;
      const bf16_t* krow = kp + (bT + k0 + r) * 1024;
      int dst = r * 64 + ((kc ^ (r & 7)) << 3);
      *(bf16x8*)&k1s[dst] = *(const bf16x8*)&krow[sh1 * 64 + kc * 8];
      *(bf16x8*)&k2s[dst] = *(const bf16x8*)&krow[sh2 * 64 + kc * 8];
    }
    // V^T tile: 128 dims x 64 keys (swizzled write)
#pragma unroll
    for (int i = 0; i < 4; ++i) {
      int c = tid + i * 256;
      int d = c >> 3, kc = c & 7;
      *(bf16x8*)&vts[d * 64 + ((kc ^ (d & 7)) << 3)] =
          *(const bf16x8*)&vth[(size_t)d * 2048 + k0 + kc * 8];
    }
    __syncthreads();
    const bool diag = (kt == bx);
    attn_step_fm(k1s, ps[w], vts, q1f, rs1, o1, diag, k0, q0, w, l15, quad);
    attn_step_fm(k2s, ps[w], vts, q2f, rs2, o2, diag, k0, q0, w, l15, quad);
  }

  // epilogue: single shuffle-reduce of row sums, then diff + LN + store
#pragma unroll
  for (int mm = 1; mm <= 8; mm <<= 1)
#pragma unroll
    for (int r = 0; r < 4; ++r) { rs1[r] += __shfl_xor(rs1[r], mm); rs2[r] += __shfl_xor(rs2[r], mm); }
  float i1[4], i2[4];
#pragma unroll
  for (int r = 0; r < 4; ++r) { i1[r] = 1.f / rs1[r]; i2[r] = 1.f / rs2[r]; }
  f32x4 od[8];
  float sum[4] = {0, 0, 0, 0}, sq[4] = {0, 0, 0, 0};
#pragma unroll
  for (int nt2 = 0; nt2 < 8; ++nt2)
#pragma unroll
    for (int r = 0; r < 4; ++r) {
      float v = declamp(o1[nt2][r] * i1[r] - lam * o2[nt2][r] * i2[r], 1e4f);
      od[nt2][r] = v;
      sum[r] += v;
      sq[r] += v * v;
    }
#pragma unroll
  for (int mm = 1; mm <= 8; mm <<= 1)
#pragma unroll
    for (int r = 0; r < 4; ++r) { sum[r] += __shfl_xor(sum[r], mm); sq[r] += __shfl_xor(sq[r], mm); }
  float mu[4], scl[4];
#pragma unroll
  for (int r = 0; r < 4; ++r) {
    mu[r] = sum[r] * (1.0f / 128.0f);
    float var = sq[r] * (1.0f / 128.0f) - mu[r] * mu[r];
    scl[r] = rsqrtf(fmaxf(var, 0.f) + LN_EPS) * ONE_MINUS_LI;
  }
#pragma unroll
  for (int nt2 = 0; nt2 < 8; ++nt2)
#pragma unroll
    for (int r = 0; r < 4; ++r) {
      int trow = q0 + w * 16 + quad * 4 + r;
      outp[(bT + trow) * 1024 + h * 128 + nt2 * 16 + l15] =
          (bf16_t)((od[nt2][r] - mu[r]) * scl[r]);
    }
}

// ==================== FALLBACK PATH (round-4, zero ws) ====================

__device__ __forceinline__ void attn_step(
    const bf16_t* __restrict__ ks, bf16_t* __restrict__ pw, const bf16_t* __restrict__ vts,
    const bf16x8* qf, float* mR, float* lR, f32x4* o,
    bool diag, int k0, int q0, int w, int l15, int quad)
{
  f32x4 sc[4];
#pragma unroll
  for (int nt = 0; nt < 4; ++nt) {
    f32x4 a = {0.f, 0.f, 0.f, 0.f};
#pragma unroll
    for (int s = 0; s < 2; ++s) {
      bf16x8 b = *(const bf16x8*)&ks[(nt * 16 + l15) * 72 + s * 32 + quad * 8];
      a = mfma16(qf[s], b, a);
    }
#pragma unroll
    for (int r = 0; r < 4; ++r) a[r] = declamp(a[r], 1e4f);
    sc[nt] = a;
  }
  if (diag) {
#pragma unroll
    for (int nt = 0; nt < 4; ++nt)
#pragma unroll
      for (int r = 0; r < 4; ++r) {
        int col = k0 + nt * 16 + l15;
        int row = q0 + w * 16 + quad * 4 + r;
        if (col > row) sc[nt][r] = -1e30f;
      }
  }
  float mx[4];
#pragma unroll
  for (int r = 0; r < 4; ++r)
    mx[r] = fmaxf(fmaxf(sc[0][r], sc[1][r]), fmaxf(sc[2][r], sc[3][r]));
#pragma unroll
  for (int mm = 1; mm <= 8; mm <<= 1)
#pragma unroll
    for (int r = 0; r < 4; ++r) mx[r] = fmaxf(mx[r], __shfl_xor(mx[r], mm));

  float mnew[4], alpha[4], rs[4];
#pragma unroll
  for (int r = 0; r < 4; ++r) {
    mnew[r] = fmaxf(mR[r], mx[r]);
    alpha[r] = __expf(mR[r] - mnew[r]);
    rs[r] = 0.f;
  }
#pragma unroll
  for (int nt = 0; nt < 4; ++nt)
#pragma unroll
    for (int r = 0; r < 4; ++r) {
      float pv = __expf(sc[nt][r] - mnew[r]);
      rs[r] += pv;
      pw[(quad * 4 + r) * 72 + nt * 16 + l15] = (bf16_t)pv;
    }
#pragma unroll
  for (int mm = 1; mm <= 8; mm <<= 1)
#pragma unroll
    for (int r = 0; r < 4; ++r) rs[r] += __shfl_xor(rs[r], mm);
#pragma unroll
  for (int r = 0; r < 4; ++r) {
    lR[r] = lR[r] * alpha[r] + rs[r];
    mR[r] = mnew[r];
  }
#pragma unroll
  for (int nt2 = 0; nt2 < 8; ++nt2)
#pragma unroll
    for (int r = 0; r < 4; ++r) o[nt2][r] *= alpha[r];
#pragma unroll
  for (int s = 0; s < 2; ++s) {
    bf16x8 pa = *(const bf16x8*)&pw[l15 * 72 + s * 32 + quad * 8];
#pragma unroll
    for (int nt2 = 0; nt2 < 8; ++nt2) {
      bf16x8 vb = *(const bf16x8*)&vts[(nt2 * 16 + l15) * 72 + s * 32 + quad * 8];
      o[nt2] = mfma16(pa, vb, o[nt2]);
    }
  }
}

template<bool A_F32, bool OUT_F32>
__global__ __launch_bounds__(256) void gemm_bt(
    const void* __restrict__ Ap,
    const float* __restrict__ W0, const float* __restrict__ W1, const float* __restrict__ W2,
    void* __restrict__ Cp0, void* __restrict__ Cp1, void* __restrict__ Cp2)
{
  const float* W = (blockIdx.z == 0) ? W0 : ((blockIdx.z == 1) ? W1 : W2);
  void*       Cv = (blockIdx.z == 0) ? Cp0 : ((blockIdx.z == 1) ? Cp1 : Cp2);
  const int K = C_EMB, N = C_EMB;
  const int n0 = blockIdx.x * 128, m0 = blockIdx.y * 128;
  __shared__ bf16_t As[128 * 40];
  __shared__ bf16_t Bs[128 * 40];
  const int tid = threadIdx.x;
  const int lane = tid & 63, w = tid >> 6;
  const int wm = w >> 1, wn = w & 1;
  const int l15 = lane & 15, quad = lane >> 4;
  const f32x4 fz = {0.f, 0.f, 0.f, 0.f};
  f32x4 acc[4][4];
#pragma unroll
  for (int i = 0; i < 4; ++i)
#pragma unroll
    for (int j = 0; j < 4; ++j) acc[i][j] = fz;

  for (int k0 = 0; k0 < K; k0 += 32) {
    if constexpr (A_F32) {
      const float* Af = (const float*)Ap;
#pragma unroll
      for (int i = 0; i < 4; ++i) {
        int c = tid + i * 256;
        int r = c >> 3, c4 = (c & 7) * 4;
        f32x4 v = *(const f32x4*)&Af[(size_t)(m0 + r) * K + k0 + c4];
        bf16x4 bv;
#pragma unroll
        for (int j = 0; j < 4; ++j) bv[j] = (bf16_t)v[j];
        *(bf16x4*)&As[r * 40 + c4] = bv;
      }
    } else {
      const bf16_t* Ab = (const bf16_t*)Ap;
#pragma unroll
      for (int i = 0; i < 2; ++i) {
        int c = tid + i * 256;
        int r = c >> 2, c8 = (c & 3) * 8;
        *(bf16x8*)&As[r * 40 + c8] = *(const bf16x8*)&Ab[(size_t)(m0 + r) * K + k0 + c8];
      }
    }
#pragma unroll
    for (int i = 0; i < 4; ++i) {
      int c = tid + i * 256;
      int r = c >> 3, c4 = (c & 7) * 4;
      f32x4 v = *(const f32x4*)&W[(size_t)(n0 + r) * K + k0 + c4];
      bf16x4 bv;
#pragma unroll
      for (int j = 0; j < 4; ++j) bv[j] = (bf16_t)v[j];
      *(bf16x4*)&Bs[r * 40 + c4] = bv;
    }
    __syncthreads();
    bf16x8 af[4], bfr[4];
#pragma unroll
    for (int i = 0; i < 4; ++i)
      af[i] = *(const bf16x8*)&As[(wm * 64 + i * 16 + l15) * 40 + quad * 8];
#pragma unroll
    for (int j = 0; j < 4; ++j)
      bfr[j] = *(const bf16x8*)&Bs[(wn * 64 + j * 16 + l15) * 40 + quad * 8];
#pragma unroll
    for (int i = 0; i < 4; ++i)
#pragma unroll
      for (int j = 0; j < 4; ++j) acc[i][j] = mfma16(af[i], bfr[j], acc[i][j]);
    __syncthreads();
  }
#pragma unroll
  for (int i = 0; i < 4; ++i)
#pragma unroll
    for (int j = 0; j < 4; ++j)
#pragma unroll
      for (int r = 0; r < 4; ++r) {
        int row = m0 + wm * 64 + i * 16 + quad * 4 + r;
        int col = n0 + wn * 64 + j * 16 + l15;
        float v = declamp(acc[i][j][r], 1e4f);
        if constexpr (OUT_F32) ((float*)Cv)[(size_t)row * N + col] = v;
        else                   ((bf16_t*)Cv)[(size_t)row * N + col] = (bf16_t)v;
      }
}

__global__ __launch_bounds__(256) void rope_rms(bf16_t* __restrict__ arr, int is_q)
{
  const int tid = threadIdx.x;
  const int g = blockIdx.x * 16 + (tid >> 4);
  const int l16 = tid & 15;
  const int t = (g >> 4) & (T_SEQ - 1);
  bf16_t* p = arr + (size_t)g * 64 + l16 * 4;
  bf16x4 xv = *(const bf16x4*)p;
  float x[4];
#pragma unroll
  for (int j = 0; j < 4; ++j) x[j] = (float)xv[j];
  float ss = x[0]*x[0] + x[1]*x[1] + x[2]*x[2] + x[3]*x[3];
#pragma unroll
  for (int mm = 1; mm <= 8; mm <<= 1) ss += __shfl_xor(ss, mm);
  const float rn = rsqrtf(fmaxf(ss, 0.f) * (1.0f / 64.0f) + RMS_EPS);
  float nrm[4], prt[4];
#pragma unroll
  for (int j = 0; j < 4; ++j) nrm[j] = x[j] * rn;
#pragma unroll
  for (int j = 0; j < 4; ++j) prt[j] = __shfl_xor(nrm[j], 8);
  const int ib = (l16 & 7) * 4;
  const float sgn = (l16 < 8) ? 1.f : -1.f;
  const float scale = is_q ? 0.125f : 1.0f;
  bf16x4 ov;
#pragma unroll
  for (int j = 0; j < 4; ++j) {
    int i = ib + j;
    float invf = expf(-(float)i * 0.28782313662425575f);
    float ang = (float)t * invf;
    float c = cosf(ang), s = sinf(ang);
    ov[j] = (bf16_t)((nrm[j] * c + sgn * prt[j] * s) * scale);
  }
  *(bf16x4*)p = ov;
}

__global__ __launch_bounds__(256) void diff_attn(
    const bf16_t* qp, const bf16_t* __restrict__ kp, const bf16_t* __restrict__ vp,
    const float* __restrict__ lq1, const float* __restrict__ lk1,
    const float* __restrict__ lq2, const float* __restrict__ lk2,
    bf16_t* outp)
{
  const int bx = blockIdx.x;
  const int h = blockIdx.y;
  const int q0 = bx * 64;
  const int tid = threadIdx.x;
  const int lane = tid & 63, w = tid >> 6;
  const int l15 = lane & 15, quad = lane >> 4;

  __shared__ bf16_t k1s[64 * 72];
  __shared__ bf16_t k2s[64 * 72];
  __shared__ bf16_t vts[128 * 72];
  __shared__ bf16_t ps[4][16 * 72];

  float e1 = lq1[lane] * lk1[lane];
  float e2 = lq2[lane] * lk2[lane];
#pragma unroll
  for (int mm = 1; mm <= 32; mm <<= 1) { e1 += __shfl_xor(e1, mm); e2 += __shfl_xor(e2, mm); }
  const float lam = expf(declamp(e1, 30.f)) - expf(declamp(e2, 30.f)) + LAMBDA_INIT;

  const int sh1 = 2 * h, sh2 = 2 * h + 1;
  const int tq = q0 + w * 16 + l15;
  const bf16_t* qrow = qp + (size_t)tq * 1024;
  bf16x8 q1f[2], q2f[2];
#pragma unroll
  for (int s = 0; s < 2; ++s) {
    q1f[s] = *(const bf16x8*)&qrow[sh1 * 64 + s * 32 + quad * 8];
    q2f[s] = *(const bf16x8*)&qrow[sh2 * 64 + s * 32 + quad * 8];
  }
  const f32x4 fz = {0.f, 0.f, 0.f, 0.f};
  f32x4 o1[8], o2[8];
  float m1[4], l1[4], m2[4], l2[4];
#pragma unroll
  for (int i = 0; i < 8; ++i) { o1[i] = fz; o2[i] = fz; }
#pragma unroll
  for (int r = 0; r < 4; ++r) { m1[r] = -1e30f; m2[r] = -1e30f; l1[r] = 0.f; l2[r] = 0.f; }

  for (int kt = 0; kt <= bx; ++kt) {
    const int k0 = kt * 64;
    __syncthreads();
#pragma unroll
    for (int i = 0; i < 2; ++i) {
      int c = tid + i * 256;
      int r = c >> 3, c8 = (c & 7) * 8;
      const bf16_t* krow = kp + (size_t)(k0 + r) * 1024;
      *(bf16x8*)&k1s[r * 72 + c8] = *(const bf16x8*)&krow[sh1 * 64 + c8];
      *(bf16x8*)&k2s[r * 72 + c8] = *(const bf16x8*)&krow[sh2 * 64 + c8];
    }
#pragma unroll
    for (int i = 0; i < 4; ++i) {
      int c = tid + i * 256;
      int r = c >> 4, d8 = (c & 15) * 8;
      bf16x8 vv = *(const bf16x8*)&vp[(size_t)(k0 + r) * 1024 + h * 128 + d8];
#pragma unroll
      for (int jj = 0; jj < 8; ++jj) vts[(d8 + jj) * 72 + r] = vv[jj];
    }
    __syncthreads();
    const bool diag = (kt == bx);
    attn_step(k1s, ps[w], vts, q1f, m1, l1, o1, diag, k0, q0, w, l15, quad);
    attn_step(k2s, ps[w], vts, q2f, m2, l2, o2, diag, k0, q0, w, l15, quad);
  }
  float i1[4], i2[4];
#pragma unroll
  for (int r = 0; r < 4; ++r) { i1[r] = 1.f / l1[r]; i2[r] = 1.f / l2[r]; }
  f32x4 od[8];
  float sum[4] = {0, 0, 0, 0}, sq[4] = {0, 0, 0, 0};
#pragma unroll
  for (int nt2 = 0; nt2 < 8; ++nt2)
#pragma unroll
    for (int r = 0; r < 4; ++r) {
      float v = declamp(o1[nt2][r] * i1[r] - lam * o2[nt2][r] * i2[r], 1e4f);
      od[nt2][r] = v;
      sum[r] += v;
      sq[r] += v * v;
    }
#pragma unroll
  for (int mm = 1; mm <= 8; mm <<= 1)
#pragma unroll
    for (int r = 0; r < 4; ++r) { sum[r] += __shfl_xor(sum[r], mm); sq[r] += __shfl_xor(sq[r], mm); }
  float mu[4], scl[4];
#pragma unroll
  for (int r = 0; r < 4; ++r) {
    mu[r] = sum[r] * (1.0f / 128.0f);
    float var = sq[r] * (1.0f / 128.0f) - mu[r] * mu[r];
    scl[r] = rsqrtf(fmaxf(var, 0.f) + LN_EPS) * ONE_MINUS_LI;
  }
#pragma unroll
  for (int nt2 = 0; nt2 < 8; ++nt2)
#pragma unroll
    for (int r = 0; r < 4; ++r) {
      int trow = q0 + w * 16 + quad * 4 + r;
      outp[(size_t)trow * 1024 + h * 128 + nt2 * 16 + l15] =
          (bf16_t)((od[nt2][r] - mu[r]) * scl[r]);
    }
}

// ==================== launch ====================
extern "C" void kernel_launch(void* const* d_in, const int* in_sizes, int n_in,
                              void* d_out, int out_size, void* d_ws, size_t ws_size,
                              hipStream_t stream) {
  const float* x     = (const float*)d_in[0];
  const float* Wq    = (const float*)d_in[1];
  const float* Wk    = (const float*)d_in[2];
  const float* Wv    = (const float*)d_in[3];
  const float* Wproj = (const float*)d_in[4];
  const float* lq1   = (const float*)d_in[5];
  const float* lk1   = (const float*)d_in[6];
  const float* lq2   = (const float*)d_in[7];
  const float* lk2   = (const float*)d_in[8];
  float* O = (float*)d_out;
  const size_t R = (size_t)T_SEQ * C_EMB;

  if (ws_size >= (size_t)40 * 1024 * 1024) {
    // ---------- FAST PATH ----------
    bf16_t* wsb = (bf16_t*)d_ws;
    bf16_t* xb  = wsb;                       // [0, 8M elems) ; reused as attn-out
    bf16_t* wqb = wsb + 8388608;
    bf16_t* wkb = wqb + 1048576;
    bf16_t* wvb = wkb + 1048576;
    bf16_t* wpb = wvb + 1048576;
    bf16_t* vt  = wpb + 1048576;             // [12M, 20M elems) = 16MB
    bf16_t* qo  = (bf16_t*)d_out;            // d_out low half
    bf16_t* ko  = qo + 8388608;              // d_out high half
    bf16_t* a   = xb;                        // attn-out over dead xb

    cvt_all<<<12288, 256, 0, stream>>>(x, Wq, Wk, Wv, Wproj, xb, wqb, wkb, wvb, wpb);
    gemm_qkv<<<dim3(8, 64, 3), 256, 0, stream>>>(xb, wqb, wkb, wvb, qo, ko, vt);
    rope_rms2<<<dim3(8192, 2), 256, 0, stream>>>(qo, ko);
    diff_attn2<<<dim3(32, 32), 256, 0, stream>>>(qo, ko, vt, lq1, lk1, lq2, lk2, a);
    gemm_proj<<<dim3(8, 64), 256, 0, stream>>>(a, wpb, O);
  } else {
    // ---------- FALLBACK (round-4 proven, zero ws) ----------
    char* Ob = (char*)d_out;
    char* Xb = (char*)d_in[0];
    const size_t MB4 = (size_t)1 << 22;
    bf16_t* qb[4] = { (bf16_t*)(Ob + 2*MB4), (bf16_t*)(Ob + 5*MB4),
                      (bf16_t*)(Xb + 0*MB4), (bf16_t*)(Xb + 3*MB4) };
    bf16_t* kb[4] = { (bf16_t*)(Ob + 3*MB4), (bf16_t*)(Ob + 6*MB4),
                      (bf16_t*)(Xb + 1*MB4), (bf16_t*)(Xb + 4*MB4) };
    bf16_t* vb[4] = { (bf16_t*)(Ob + 4*MB4), (bf16_t*)(Ob + 7*MB4),
                      (bf16_t*)(Xb + 2*MB4), (bf16_t*)(Xb + 5*MB4) };
    for (int b = 0; b < 4; ++b) {
      const float* xbp = x + (size_t)b * R;
      gemm_bt<true, false><<<dim3(8, 16, 3), 256, 0, stream>>>(
          xbp, Wq, Wk, Wv, qb[b], kb[b], vb[b]);
      rope_rms<<<2048, 256, 0, stream>>>(qb[b], 1);
      rope_rms<<<2048, 256, 0, stream>>>(kb[b], 0);
      diff_attn<<<dim3(32, 8), 256, 0, stream>>>(qb[b], kb[b], vb[b],
                                                 lq1, lk1, lq2, lk2, qb[b]);
      gemm_bt<false, true><<<dim3(8, 16, 1), 256, 0, stream>>>(
          qb[b], Wproj, Wproj, Wproj, O + (size_t)b * R, nullptr, nullptr);
    }
  }
}

// Round 8
// 514.897 us; speedup vs baseline: 2.0903x; 2.0903x over previous
//
#include <hip/hip_runtime.h>
#include <hip/hip_bf16.h>
#include <math.h>

// Differential causal self-attention. ALL I/O float32; internal bf16 MFMA.
// FAST PATH (ws_size >= 40MB): batch-merged launches, 6 dispatches.
//   ws: [0,16M) xb (x as bf16; reused as attn-out after QKV consumes it)
//       [16M,24M) Wq,Wk,Wv,Wproj as bf16 (2MB each)
//       [24M,40M) vt = V transposed per batch: vt[b][dim 0..1023][t 0..2047]
//   d_out: [0,16M) q bf16, [16M,32M) k bf16 (dead before proj writes f32)
// Attention: FIXED-max softmax (rmsnorm => |S|<=8(1+eps), m=9 const).
// All attn LDS tiles: pitch 64 + XOR chunk swizzle -> 0 bank conflicts
// (verified round 7). NO launch_bounds cap: round 7's (256,4) forced
// VGPR=64 -> accumulator spills -> 1.2GB scratch traffic, 2x regression.
// FALLBACK (small ws): round-4 proven per-batch pipeline, zero ws usage.

typedef __bf16 bf16_t;
typedef __bf16 bf16x8 __attribute__((ext_vector_type(8)));
typedef __bf16 bf16x4 __attribute__((ext_vector_type(4)));
typedef float  f32x4  __attribute__((ext_vector_type(4)));

#define T_SEQ 2048
#define C_EMB 1024
static constexpr float LAMBDA_INIT = 0.6192834728526787f;   // 0.8 - 0.6*exp(-1.2)
static constexpr float ONE_MINUS_LI = 0.3807165271473213f;
static constexpr float RMS_EPS = 1.1920928955078125e-07f;
static constexpr float LN_EPS = 1e-5f;
static constexpr float M_FIX = 9.0f;    // fixed softmax max (|S| <= ~8.05)

__device__ __forceinline__ f32x4 mfma16(bf16x8 a, bf16x8 b, f32x4 c) {
  return __builtin_amdgcn_mfma_f32_16x16x32_bf16(a, b, c, 0, 0, 0);
}
__device__ __forceinline__ float declamp(float v, float lim) {
  return fminf(fmaxf(v, -lim), lim);   // IEEE min/max: NaN firewall too
}

// ==================== FAST PATH ====================

// ---- one-shot f32 -> bf16 convert: x (8M) + 4 weights (1M each) ----
__global__ __launch_bounds__(256) void cvt_all(
    const float* __restrict__ x,  const float* __restrict__ Wq,
    const float* __restrict__ Wk, const float* __restrict__ Wv,
    const float* __restrict__ Wp,
    bf16_t* __restrict__ xb,  bf16_t* __restrict__ wqb, bf16_t* __restrict__ wkb,
    bf16_t* __restrict__ wvb, bf16_t* __restrict__ wpb)
{
  size_t i4 = ((size_t)blockIdx.x * 256 + threadIdx.x) * 4;
  const float* s; bf16_t* d; size_t off;
  if      (i4 <  8388608) { s = x;  d = xb;  off = i4; }
  else if (i4 <  9437184) { s = Wq; d = wqb; off = i4 - 8388608; }
  else if (i4 < 10485760) { s = Wk; d = wkb; off = i4 - 9437184; }
  else if (i4 < 11534336) { s = Wv; d = wvb; off = i4 - 10485760; }
  else                    { s = Wp; d = wpb; off = i4 - 11534336; }
  f32x4 v = *(const f32x4*)(s + off);
  bf16x4 bv;
#pragma unroll
  for (int j = 0; j < 4; ++j) bv[j] = (bf16_t)v[j];
  *(bf16x4*)(d + off) = bv;
}

// ---- shared GEMM mainloop: acc = A(128 rows) @ W(128 rows)^T over K=1024 ----
__device__ __forceinline__ void gemm_core(
    const bf16_t* __restrict__ A, const bf16_t* __restrict__ W,
    bf16_t* As, bf16_t* Bs, f32x4 acc[4][4], int m0, int n0)
{
  const int tid = threadIdx.x;
  const int lane = tid & 63, w = tid >> 6;
  const int wm = w >> 1, wn = w & 1;
  const int l15 = lane & 15, quad = lane >> 4;
  for (int k0 = 0; k0 < C_EMB; k0 += 32) {
#pragma unroll
    for (int i = 0; i < 2; ++i) {
      int c = tid + i * 256;            // 512 x 16B chunks
      int r = c >> 2, c8 = (c & 3) * 8;
      *(bf16x8*)&As[r * 40 + c8] = *(const bf16x8*)&A[(size_t)(m0 + r) * C_EMB + k0 + c8];
      *(bf16x8*)&Bs[r * 40 + c8] = *(const bf16x8*)&W[(size_t)(n0 + r) * C_EMB + k0 + c8];
    }
    __syncthreads();
    bf16x8 af[4], bfr[4];
#pragma unroll
    for (int i = 0; i < 4; ++i)
      af[i] = *(const bf16x8*)&As[(wm * 64 + i * 16 + l15) * 40 + quad * 8];
#pragma unroll
    for (int j = 0; j < 4; ++j)
      bfr[j] = *(const bf16x8*)&Bs[(wn * 64 + j * 16 + l15) * 40 + quad * 8];
#pragma unroll
    for (int i = 0; i < 4; ++i)
#pragma unroll
      for (int j = 0; j < 4; ++j) acc[i][j] = mfma16(af[i], bfr[j], acc[i][j]);
    __syncthreads();
  }
}

// ---- QKV gemm over all batches (M=8192). z=0 q, z=1 k (row-major bf16),
//      z=2 v written TRANSPOSED: vt[b][col][t] (bf16x4 along t, no LDS) ----
__global__ __launch_bounds__(256) void gemm_qkv(
    const bf16_t* __restrict__ A,
    const bf16_t* __restrict__ Wqb, const bf16_t* __restrict__ Wkb, const bf16_t* __restrict__ Wvb,
    bf16_t* __restrict__ qo, bf16_t* __restrict__ ko, bf16_t* __restrict__ vt)
{
  const int z = blockIdx.z;
  const bf16_t* W = (z == 0) ? Wqb : ((z == 1) ? Wkb : Wvb);
  const int n0 = blockIdx.x * 128, m0 = blockIdx.y * 128;
  __shared__ bf16_t As[128 * 40];
  __shared__ bf16_t Bs[128 * 40];
  const int lane = threadIdx.x & 63, w = threadIdx.x >> 6;
  const int wm = w >> 1, wn = w & 1;
  const int l15 = lane & 15, quad = lane >> 4;
  const f32x4 fz = {0.f, 0.f, 0.f, 0.f};
  f32x4 acc[4][4];
#pragma unroll
  for (int i = 0; i < 4; ++i)
#pragma unroll
    for (int j = 0; j < 4; ++j) acc[i][j] = fz;
  gemm_core(A, W, As, Bs, acc, m0, n0);

  if (z < 2) {
    bf16_t* C = z ? ko : qo;
#pragma unroll
    for (int i = 0; i < 4; ++i)
#pragma unroll
      for (int j = 0; j < 4; ++j)
#pragma unroll
        for (int r = 0; r < 4; ++r) {
          int row = m0 + wm * 64 + i * 16 + quad * 4 + r;
          int col = n0 + wn * 64 + j * 16 + l15;
          C[(size_t)row * C_EMB + col] = (bf16_t)declamp(acc[i][j][r], 1e4f);
        }
  } else {
#pragma unroll
    for (int i = 0; i < 4; ++i)
#pragma unroll
      for (int j = 0; j < 4; ++j) {
        int row = m0 + wm * 64 + i * 16 + quad * 4;   // multiple of 4, same batch
        int col = n0 + wn * 64 + j * 16 + l15;
        bf16x4 pv;
#pragma unroll
        for (int r = 0; r < 4; ++r) pv[r] = (bf16_t)declamp(acc[i][j][r], 1e4f);
        size_t idx = (size_t)(row >> 11) * 2097152 + (size_t)col * 2048 + (row & 2047);
        *(bf16x4*)&vt[idx] = pv;
      }
  }
}

// ---- proj gemm: bf16 A/W -> f32 out ----
__global__ __launch_bounds__(256) void gemm_proj(
    const bf16_t* __restrict__ A, const bf16_t* __restrict__ Wpb, float* __restrict__ C)
{
  const int n0 = blockIdx.x * 128, m0 = blockIdx.y * 128;
  __shared__ bf16_t As[128 * 40];
  __shared__ bf16_t Bs[128 * 40];
  const int lane = threadIdx.x & 63, w = threadIdx.x >> 6;
  const int wm = w >> 1, wn = w & 1;
  const int l15 = lane & 15, quad = lane >> 4;
  const f32x4 fz = {0.f, 0.f, 0.f, 0.f};
  f32x4 acc[4][4];
#pragma unroll
  for (int i = 0; i < 4; ++i)
#pragma unroll
    for (int j = 0; j < 4; ++j) acc[i][j] = fz;
  gemm_core(A, Wpb, As, Bs, acc, m0, n0);
#pragma unroll
  for (int i = 0; i < 4; ++i)
#pragma unroll
    for (int j = 0; j < 4; ++j)
#pragma unroll
      for (int r = 0; r < 4; ++r) {
        int row = m0 + wm * 64 + i * 16 + quad * 4 + r;
        int col = n0 + wn * 64 + j * 16 + l15;
        C[(size_t)row * C_EMB + col] = declamp(acc[i][j][r], 1e4f);
      }
}

// ---- RMSNorm + RoPE in place, q and k in one launch (blockIdx.y) ----
__global__ __launch_bounds__(256) void rope_rms2(bf16_t* __restrict__ q, bf16_t* __restrict__ k)
{
  bf16_t* arr = blockIdx.y ? k : q;
  const float scale = blockIdx.y ? 1.0f : 0.125f;   // q gets 1/sqrt(64)
  const int tid = threadIdx.x;
  const int g = blockIdx.x * 16 + (tid >> 4);       // row*16 + sh, row in [0,8192)
  const int l16 = tid & 15;
  const int t = (g >> 4) & (T_SEQ - 1);
  bf16_t* p = arr + (size_t)g * 64 + l16 * 4;

  bf16x4 xv = *(const bf16x4*)p;
  float x[4];
#pragma unroll
  for (int j = 0; j < 4; ++j) x[j] = (float)xv[j];
  float ss = x[0]*x[0] + x[1]*x[1] + x[2]*x[2] + x[3]*x[3];
#pragma unroll
  for (int mm = 1; mm <= 8; mm <<= 1) ss += __shfl_xor(ss, mm);
  const float rn = rsqrtf(fmaxf(ss, 0.f) * (1.0f / 64.0f) + RMS_EPS);
  float nrm[4], prt[4];
#pragma unroll
  for (int j = 0; j < 4; ++j) nrm[j] = x[j] * rn;
#pragma unroll
  for (int j = 0; j < 4; ++j) prt[j] = __shfl_xor(nrm[j], 8);

  const int ib = (l16 & 7) * 4;
  const float sgn = (l16 < 8) ? 1.f : -1.f;
  bf16x4 ov;
#pragma unroll
  for (int j = 0; j < 4; ++j) {
    int i = ib + j;
    float invf = expf(-(float)i * 0.28782313662425575f);  // 10000^(-i/32)
    float ang = (float)t * invf;
    float c = cosf(ang), s = sinf(ang);
    ov[j] = (bf16_t)((nrm[j] * c + sgn * prt[j] * s) * scale);
  }
  *(bf16x4*)p = ov;
}

// ---- FIXED-MAX attention step. All tiles pitch 64, XOR chunk swizzle:
//      element (row, col=c*8+j) stored at row*64 + ((c ^ (row&7))*8 + j) ----
__device__ __forceinline__ void attn_step_fm(
    const bf16_t* __restrict__ ks, bf16_t* __restrict__ pw, const bf16_t* __restrict__ vts,
    const bf16x8* qf, float* rsum, f32x4* o,
    bool diag, int k0, int q0, int w, int l15, int quad)
{
  const int xs = l15 & 7;        // row&7 for rows ≡ l15 (mod 16)
  f32x4 sc[4];
#pragma unroll
  for (int nt = 0; nt < 4; ++nt) {
    f32x4 a = {0.f, 0.f, 0.f, 0.f};
#pragma unroll
    for (int s = 0; s < 2; ++s) {
      bf16x8 b = *(const bf16x8*)&ks[(nt * 16 + l15) * 64 + ((((s << 2) + quad) ^ xs) << 3)];
      a = mfma16(qf[s], b, a);
    }
#pragma unroll
    for (int r = 0; r < 4; ++r) a[r] = declamp(a[r], 30.f);   // NaN firewall
    sc[nt] = a;
  }
  if (diag) {
#pragma unroll
    for (int nt = 0; nt < 4; ++nt)
#pragma unroll
      for (int r = 0; r < 4; ++r) {
        int col = k0 + nt * 16 + l15;
        int row = q0 + w * 16 + quad * 4 + r;
        if (col > row) sc[nt][r] = -1e30f;
      }
  }
  // P = exp(S - M_FIX); per-lane row partial sums (reduced once in epilogue)
#pragma unroll
  for (int nt = 0; nt < 4; ++nt)
#pragma unroll
    for (int r = 0; r < 4; ++r) {
      float pv = __expf(sc[nt][r] - M_FIX);
      rsum[r] += pv;
      int row = quad * 4 + r;
      int col = nt * 16 + l15;
      pw[row * 64 + ((((col >> 3) ^ (row & 7)) << 3) | (col & 7))] = (bf16_t)pv;
    }
  // O += P(16x64) @ V(64x128)
#pragma unroll
  for (int s = 0; s < 2; ++s) {
    bf16x8 pa = *(const bf16x8*)&pw[l15 * 64 + ((((s << 2) + quad) ^ xs) << 3)];
#pragma unroll
    for (int nt2 = 0; nt2 < 8; ++nt2) {
      bf16x8 vb = *(const bf16x8*)&vts[(nt2 * 16 + l15) * 64 + ((((s << 2) + quad) ^ xs) << 3)];
      o[nt2] = mfma16(pa, vb, o[nt2]);
    }
  }
}

// ---- batch-merged diff attention; V staged from pre-transposed vt ----
// LDS = 40960B. Default launch bounds: VGPR ~140, no spills (round 7 lesson).
__global__ __launch_bounds__(256) void diff_attn2(
    const bf16_t* __restrict__ qp, const bf16_t* __restrict__ kp, const bf16_t* __restrict__ vtp,
    const float* __restrict__ lq1, const float* __restrict__ lk1,
    const float* __restrict__ lq2, const float* __restrict__ lk2,
    bf16_t* __restrict__ outp)
{
  const int bx = 31 - blockIdx.x;          // longest chains dispatched first
  const int b = blockIdx.y >> 3, h = blockIdx.y & 7;
  const int q0 = bx * 64;
  const int tid = threadIdx.x;
  const int lane = tid & 63, w = tid >> 6;
  const int l15 = lane & 15, quad = lane >> 4;
  const size_t bT = (size_t)b * T_SEQ;
  const bf16_t* vth = vtp + (size_t)b * 2097152 + (size_t)(h * 128) * 2048;

  __shared__ bf16_t k1s[64 * 64];          // pitch 64, XOR chunk swizzle
  __shared__ bf16_t k2s[64 * 64];
  __shared__ bf16_t vts[128 * 64];
  __shared__ bf16_t ps[4][16 * 64];

  float e1 = lq1[lane] * lk1[lane];
  float e2 = lq2[lane] * lk2[lane];
#pragma unroll
  for (int mm = 1; mm <= 32; mm <<= 1) { e1 += __shfl_xor(e1, mm); e2 += __shfl_xor(e2, mm); }
  const float lam = expf(declamp(e1, 30.f)) - expf(declamp(e2, 30.f)) + LAMBDA_INIT;

  const int sh1 = 2 * h, sh2 = 2 * h + 1;
  const int tq = q0 + w * 16 + l15;
  const bf16_t* qrow = qp + (bT + tq) * 1024;
  bf16x8 q1f[2], q2f[2];
#pragma unroll
  for (int s = 0; s < 2; ++s) {
    q1f[s] = *(const bf16x8*)&qrow[sh1 * 64 + s * 32 + quad * 8];
    q2f[s] = *(const bf16x8*)&qrow[sh2 * 64 + s * 32 + quad * 8];
  }

  const f32x4 fz = {0.f, 0.f, 0.f, 0.f};
  f32x4 o1[8], o2[8];
  float rs1[4] = {0, 0, 0, 0}, rs2[4] = {0, 0, 0, 0};
#pragma unroll
  for (int i = 0; i < 8; ++i) { o1[i] = fz; o2[i] = fz; }

  for (int kt = 0; kt <= bx; ++kt) {
    const int k0 = kt * 64;
    __syncthreads();
    // K tiles (swizzled write: chunk ^ (row&7))
#pragma unroll
    for (int i = 0; i < 2; ++i) {
      int c = tid + i * 256;
      int r = c >> 3, kc = c & 7;
      const bf16_t* krow = kp + (bT + k0 + r) * 1024;
      int dst = r * 64 + ((kc ^ (r & 7)) << 3);
      *(bf16x8*)&k1s[dst] = *(const bf16x8*)&krow[sh1 * 64 + kc * 8];
      *(bf16x8*)&k2s[dst] = *(const bf16x8*)&krow[sh2 * 64 + kc * 8];
    }
    // V^T tile: 128 dims x 64 keys (swizzled write)
#pragma unroll
    for (int i = 0; i < 4; ++i) {
      int c = tid + i * 256;
      int d = c >> 3, kc = c & 7;
      *(bf16x8*)&vts[d * 64 + ((kc ^ (d & 7)) << 3)] =
          *(const bf16x8*)&vth[(size_t)d * 2048 + k0 + kc * 8];
    }
    __syncthreads();
    const bool diag = (kt == bx);
    attn_step_fm(k1s, ps[w], vts, q1f, rs1, o1, diag, k0, q0, w, l15, quad);
    attn_step_fm(k2s, ps[w], vts, q2f, rs2, o2, diag, k0, q0, w, l15, quad);
  }

  // epilogue: single shuffle-reduce of row sums, then diff + LN + store
#pragma unroll
  for (int mm = 1; mm <= 8; mm <<= 1)
#pragma unroll
    for (int r = 0; r < 4; ++r) { rs1[r] += __shfl_xor(rs1[r], mm); rs2[r] += __shfl_xor(rs2[r], mm); }
  float i1[4], i2[4];
#pragma unroll
  for (int r = 0; r < 4; ++r) { i1[r] = 1.f / rs1[r]; i2[r] = 1.f / rs2[r]; }
  f32x4 od[8];
  float sum[4] = {0, 0, 0, 0}, sq[4] = {0, 0, 0, 0};
#pragma unroll
  for (int nt2 = 0; nt2 < 8; ++nt2)
#pragma unroll
    for (int r = 0; r < 4; ++r) {
      float v = declamp(o1[nt2][r] * i1[r] - lam * o2[nt2][r] * i2[r], 1e4f);
      od[nt2][r] = v;
      sum[r] += v;
      sq[r] += v * v;
    }
#pragma unroll
  for (int mm = 1; mm <= 8; mm <<= 1)
#pragma unroll
    for (int r = 0; r < 4; ++r) { sum[r] += __shfl_xor(sum[r], mm); sq[r] += __shfl_xor(sq[r], mm); }
  float mu[4], scl[4];
#pragma unroll
  for (int r = 0; r < 4; ++r) {
    mu[r] = sum[r] * (1.0f / 128.0f);
    float var = sq[r] * (1.0f / 128.0f) - mu[r] * mu[r];
    scl[r] = rsqrtf(fmaxf(var, 0.f) + LN_EPS) * ONE_MINUS_LI;
  }
#pragma unroll
  for (int nt2 = 0; nt2 < 8; ++nt2)
#pragma unroll
    for (int r = 0; r < 4; ++r) {
      int trow = q0 + w * 16 + quad * 4 + r;
      outp[(bT + trow) * 1024 + h * 128 + nt2 * 16 + l15] =
          (bf16_t)((od[nt2][r] - mu[r]) * scl[r]);
    }
}

// ==================== FALLBACK PATH (round-4, zero ws) ====================

__device__ __forceinline__ void attn_step(
    const bf16_t* __restrict__ ks, bf16_t* __restrict__ pw, const bf16_t* __restrict__ vts,
    const bf16x8* qf, float* mR, float* lR, f32x4* o,
    bool diag, int k0, int q0, int w, int l15, int quad)
{
  f32x4 sc[4];
#pragma unroll
  for (int nt = 0; nt < 4; ++nt) {
    f32x4 a = {0.f, 0.f, 0.f, 0.f};
#pragma unroll
    for (int s = 0; s < 2; ++s) {
      bf16x8 b = *(const bf16x8*)&ks[(nt * 16 + l15) * 72 + s * 32 + quad * 8];
      a = mfma16(qf[s], b, a);
    }
#pragma unroll
    for (int r = 0; r < 4; ++r) a[r] = declamp(a[r], 1e4f);
    sc[nt] = a;
  }
  if (diag) {
#pragma unroll
    for (int nt = 0; nt < 4; ++nt)
#pragma unroll
      for (int r = 0; r < 4; ++r) {
        int col = k0 + nt * 16 + l15;
        int row = q0 + w * 16 + quad * 4 + r;
        if (col > row) sc[nt][r] = -1e30f;
      }
  }
  float mx[4];
#pragma unroll
  for (int r = 0; r < 4; ++r)
    mx[r] = fmaxf(fmaxf(sc[0][r], sc[1][r]), fmaxf(sc[2][r], sc[3][r]));
#pragma unroll
  for (int mm = 1; mm <= 8; mm <<= 1)
#pragma unroll
    for (int r = 0; r < 4; ++r) mx[r] = fmaxf(mx[r], __shfl_xor(mx[r], mm));

  float mnew[4], alpha[4], rs[4];
#pragma unroll
  for (int r = 0; r < 4; ++r) {
    mnew[r] = fmaxf(mR[r], mx[r]);
    alpha[r] = __expf(mR[r] - mnew[r]);
    rs[r] = 0.f;
  }
#pragma unroll
  for (int nt = 0; nt < 4; ++nt)
#pragma unroll
    for (int r = 0; r < 4; ++r) {
      float pv = __expf(sc[nt][r] - mnew[r]);
      rs[r] += pv;
      pw[(quad * 4 + r) * 72 + nt * 16 + l15] = (bf16_t)pv;
    }
#pragma unroll
  for (int mm = 1; mm <= 8; mm <<= 1)
#pragma unroll
    for (int r = 0; r < 4; ++r) rs[r] += __shfl_xor(rs[r], mm);
#pragma unroll
  for (int r = 0; r < 4; ++r) {
    lR[r] = lR[r] * alpha[r] + rs[r];
    mR[r] = mnew[r];
  }
#pragma unroll
  for (int nt2 = 0; nt2 < 8; ++nt2)
#pragma unroll
    for (int r = 0; r < 4; ++r) o[nt2][r] *= alpha[r];
#pragma unroll
  for (int s = 0; s < 2; ++s) {
    bf16x8 pa = *(const bf16x8*)&pw[l15 * 72 + s * 32 + quad * 8];
#pragma unroll
    for (int nt2 = 0; nt2 < 8; ++nt2) {
      bf16x8 vb = *(const bf16x8*)&vts[(nt2 * 16 + l15) * 72 + s * 32 + quad * 8];
      o[nt2] = mfma16(pa, vb, o[nt2]);
    }
  }
}

template<bool A_F32, bool OUT_F32>
__global__ __launch_bounds__(256) void gemm_bt(
    const void* __restrict__ Ap,
    const float* __restrict__ W0, const float* __restrict__ W1, const float* __restrict__ W2,
    void* __restrict__ Cp0, void* __restrict__ Cp1, void* __restrict__ Cp2)
{
  const float* W = (blockIdx.z == 0) ? W0 : ((blockIdx.z == 1) ? W1 : W2);
  void*       Cv = (blockIdx.z == 0) ? Cp0 : ((blockIdx.z == 1) ? Cp1 : Cp2);
  const int K = C_EMB, N = C_EMB;
  const int n0 = blockIdx.x * 128, m0 = blockIdx.y * 128;
  __shared__ bf16_t As[128 * 40];
  __shared__ bf16_t Bs[128 * 40];
  const int tid = threadIdx.x;
  const int lane = tid & 63, w = tid >> 6;
  const int wm = w >> 1, wn = w & 1;
  const int l15 = lane & 15, quad = lane >> 4;
  const f32x4 fz = {0.f, 0.f, 0.f, 0.f};
  f32x4 acc[4][4];
#pragma unroll
  for (int i = 0; i < 4; ++i)
#pragma unroll
    for (int j = 0; j < 4; ++j) acc[i][j] = fz;

  for (int k0 = 0; k0 < K; k0 += 32) {
    if constexpr (A_F32) {
      const float* Af = (const float*)Ap;
#pragma unroll
      for (int i = 0; i < 4; ++i) {
        int c = tid + i * 256;
        int r = c >> 3, c4 = (c & 7) * 4;
        f32x4 v = *(const f32x4*)&Af[(size_t)(m0 + r) * K + k0 + c4];
        bf16x4 bv;
#pragma unroll
        for (int j = 0; j < 4; ++j) bv[j] = (bf16_t)v[j];
        *(bf16x4*)&As[r * 40 + c4] = bv;
      }
    } else {
      const bf16_t* Ab = (const bf16_t*)Ap;
#pragma unroll
      for (int i = 0; i < 2; ++i) {
        int c = tid + i * 256;
        int r = c >> 2, c8 = (c & 3) * 8;
        *(bf16x8*)&As[r * 40 + c8] = *(const bf16x8*)&Ab[(size_t)(m0 + r) * K + k0 + c8];
      }
    }
#pragma unroll
    for (int i = 0; i < 4; ++i) {
      int c = tid + i * 256;
      int r = c >> 3, c4 = (c & 7) * 4;
      f32x4 v = *(const f32x4*)&W[(size_t)(n0 + r) * K + k0 + c4];
      bf16x4 bv;
#pragma unroll
      for (int j = 0; j < 4; ++j) bv[j] = (bf16_t)v[j];
      *(bf16x4*)&Bs[r * 40 + c4] = bv;
    }
    __syncthreads();
    bf16x8 af[4], bfr[4];
#pragma unroll
    for (int i = 0; i < 4; ++i)
      af[i] = *(const bf16x8*)&As[(wm * 64 + i * 16 + l15) * 40 + quad * 8];
#pragma unroll
    for (int j = 0; j < 4; ++j)
      bfr[j] = *(const bf16x8*)&Bs[(wn * 64 + j * 16 + l15) * 40 + quad * 8];
#pragma unroll
    for (int i = 0; i < 4; ++i)
#pragma unroll
      for (int j = 0; j < 4; ++j) acc[i][j] = mfma16(af[i], bfr[j], acc[i][j]);
    __syncthreads();
  }
#pragma unroll
  for (int i = 0; i < 4; ++i)
#pragma unroll
    for (int j = 0; j < 4; ++j)
#pragma unroll
      for (int r = 0; r < 4; ++r) {
        int row = m0 + wm * 64 + i * 16 + quad * 4 + r;
        int col = n0 + wn * 64 + j * 16 + l15;
        float v = declamp(acc[i][j][r], 1e4f);
        if constexpr (OUT_F32) ((float*)Cv)[(size_t)row * N + col] = v;
        else                   ((bf16_t*)Cv)[(size_t)row * N + col] = (bf16_t)v;
      }
}

__global__ __launch_bounds__(256) void rope_rms(bf16_t* __restrict__ arr, int is_q)
{
  const int tid = threadIdx.x;
  const int g = blockIdx.x * 16 + (tid >> 4);
  const int l16 = tid & 15;
  const int t = (g >> 4) & (T_SEQ - 1);
  bf16_t* p = arr + (size_t)g * 64 + l16 * 4;
  bf16x4 xv = *(const bf16x4*)p;
  float x[4];
#pragma unroll
  for (int j = 0; j < 4; ++j) x[j] = (float)xv[j];
  float ss = x[0]*x[0] + x[1]*x[1] + x[2]*x[2] + x[3]*x[3];
#pragma unroll
  for (int mm = 1; mm <= 8; mm <<= 1) ss += __shfl_xor(ss, mm);
  const float rn = rsqrtf(fmaxf(ss, 0.f) * (1.0f / 64.0f) + RMS_EPS);
  float nrm[4], prt[4];
#pragma unroll
  for (int j = 0; j < 4; ++j) nrm[j] = x[j] * rn;
#pragma unroll
  for (int j = 0; j < 4; ++j) prt[j] = __shfl_xor(nrm[j], 8);
  const int ib = (l16 & 7) * 4;
  const float sgn = (l16 < 8) ? 1.f : -1.f;
  const float scale = is_q ? 0.125f : 1.0f;
  bf16x4 ov;
#pragma unroll
  for (int j = 0; j < 4; ++j) {
    int i = ib + j;
    float invf = expf(-(float)i * 0.28782313662425575f);
    float ang = (float)t * invf;
    float c = cosf(ang), s = sinf(ang);
    ov[j] = (bf16_t)((nrm[j] * c + sgn * prt[j] * s) * scale);
  }
  *(bf16x4*)p = ov;
}

__global__ __launch_bounds__(256) void diff_attn(
    const bf16_t* qp, const bf16_t* __restrict__ kp, const bf16_t* __restrict__ vp,
    const float* __restrict__ lq1, const float* __restrict__ lk1,
    const float* __restrict__ lq2, const float* __restrict__ lk2,
    bf16_t* outp)
{
  const int bx = blockIdx.x;
  const int h = blockIdx.y;
  const int q0 = bx * 64;
  const int tid = threadIdx.x;
  const int lane = tid & 63, w = tid >> 6;
  const int l15 = lane & 15, quad = lane >> 4;

  __shared__ bf16_t k1s[64 * 72];
  __shared__ bf16_t k2s[64 * 72];
  __shared__ bf16_t vts[128 * 72];
  __shared__ bf16_t ps[4][16 * 72];

  float e1 = lq1[lane] * lk1[lane];
  float e2 = lq2[lane] * lk2[lane];
#pragma unroll
  for (int mm = 1; mm <= 32; mm <<= 1) { e1 += __shfl_xor(e1, mm); e2 += __shfl_xor(e2, mm); }
  const float lam = expf(declamp(e1, 30.f)) - expf(declamp(e2, 30.f)) + LAMBDA_INIT;

  const int sh1 = 2 * h, sh2 = 2 * h + 1;
  const int tq = q0 + w * 16 + l15;
  const bf16_t* qrow = qp + (size_t)tq * 1024;
  bf16x8 q1f[2], q2f[2];
#pragma unroll
  for (int s = 0; s < 2; ++s) {
    q1f[s] = *(const bf16x8*)&qrow[sh1 * 64 + s * 32 + quad * 8];
    q2f[s] = *(const bf16x8*)&qrow[sh2 * 64 + s * 32 + quad * 8];
  }
  const f32x4 fz = {0.f, 0.f, 0.f, 0.f};
  f32x4 o1[8], o2[8];
  float m1[4], l1[4], m2[4], l2[4];
#pragma unroll
  for (int i = 0; i < 8; ++i) { o1[i] = fz; o2[i] = fz; }
#pragma unroll
  for (int r = 0; r < 4; ++r) { m1[r] = -1e30f; m2[r] = -1e30f; l1[r] = 0.f; l2[r] = 0.f; }

  for (int kt = 0; kt <= bx; ++kt) {
    const int k0 = kt * 64;
    __syncthreads();
#pragma unroll
    for (int i = 0; i < 2; ++i) {
      int c = tid + i * 256;
      int r = c >> 3, c8 = (c & 7) * 8;
      const bf16_t* krow = kp + (size_t)(k0 + r) * 1024;
      *(bf16x8*)&k1s[r * 72 + c8] = *(const bf16x8*)&krow[sh1 * 64 + c8];
      *(bf16x8*)&k2s[r * 72 + c8] = *(const bf16x8*)&krow[sh2 * 64 + c8];
    }
#pragma unroll
    for (int i = 0; i < 4; ++i) {
      int c = tid + i * 256;
      int r = c >> 4, d8 = (c & 15) * 8;
      bf16x8 vv = *(const bf16x8*)&vp[(size_t)(k0 + r) * 1024 + h * 128 + d8];
#pragma unroll
      for (int jj = 0; jj < 8; ++jj) vts[(d8 + jj) * 72 + r] = vv[jj];
    }
    __syncthreads();
    const bool diag = (kt == bx);
    attn_step(k1s, ps[w], vts, q1f, m1, l1, o1, diag, k0, q0, w, l15, quad);
    attn_step(k2s, ps[w], vts, q2f, m2, l2, o2, diag, k0, q0, w, l15, quad);
  }
  float i1[4], i2[4];
#pragma unroll
  for (int r = 0; r < 4; ++r) { i1[r] = 1.f / l1[r]; i2[r] = 1.f / l2[r]; }
  f32x4 od[8];
  float sum[4] = {0, 0, 0, 0}, sq[4] = {0, 0, 0, 0};
#pragma unroll
  for (int nt2 = 0; nt2 < 8; ++nt2)
#pragma unroll
    for (int r = 0; r < 4; ++r) {
      float v = declamp(o1[nt2][r] * i1[r] - lam * o2[nt2][r] * i2[r], 1e4f);
      od[nt2][r] = v;
      sum[r] += v;
      sq[r] += v * v;
    }
#pragma unroll
  for (int mm = 1; mm <= 8; mm <<= 1)
#pragma unroll
    for (int r = 0; r < 4; ++r) { sum[r] += __shfl_xor(sum[r], mm); sq[r] += __shfl_xor(sq[r], mm); }
  float mu[4], scl[4];
#pragma unroll
  for (int r = 0; r < 4; ++r) {
    mu[r] = sum[r] * (1.0f / 128.0f);
    float var = sq[r] * (1.0f / 128.0f) - mu[r] * mu[r];
    scl[r] = rsqrtf(fmaxf(var, 0.f) + LN_EPS) * ONE_MINUS_LI;
  }
#pragma unroll
  for (int nt2 = 0; nt2 < 8; ++nt2)
#pragma unroll
    for (int r = 0; r < 4; ++r) {
      int trow = q0 + w * 16 + quad * 4 + r;
      outp[(size_t)trow * 1024 + h * 128 + nt2 * 16 + l15] =
          (bf16_t)((od[nt2][r] - mu[r]) * scl[r]);
    }
}

// ==================== launch ====================
extern "C" void kernel_launch(void* const* d_in, const int* in_sizes, int n_in,
                              void* d_out, int out_size, void* d_ws, size_t ws_size,
                              hipStream_t stream) {
  const float* x     = (const float*)d_in[0];
  const float* Wq    = (const float*)d_in[1];
  const float* Wk    = (const float*)d_in[2];
  const float* Wv    = (const float*)d_in[3];
  const float* Wproj = (const float*)d_in[4];
  const float* lq1   = (const float*)d_in[5];
  const float* lk1   = (const float*)d_in[6];
  const float* lq2   = (const float*)d_in[7];
  const float* lk2   = (const float*)d_in[8];
  float* O = (float*)d_out;
  const size_t R = (size_t)T_SEQ * C_EMB;

  if (ws_size >= (size_t)40 * 1024 * 1024) {
    // ---------- FAST PATH ----------
    bf16_t* wsb = (bf16_t*)d_ws;
    bf16_t* xb  = wsb;                       // [0, 8M elems) ; reused as attn-out
    bf16_t* wqb = wsb + 8388608;
    bf16_t* wkb = wqb + 1048576;
    bf16_t* wvb = wkb + 1048576;
    bf16_t* wpb = wvb + 1048576;
    bf16_t* vt  = wpb + 1048576;             // [12M, 20M elems) = 16MB
    bf16_t* qo  = (bf16_t*)d_out;            // d_out low half
    bf16_t* ko  = qo + 8388608;              // d_out high half
    bf16_t* a   = xb;                        // attn-out over dead xb

    cvt_all<<<12288, 256, 0, stream>>>(x, Wq, Wk, Wv, Wproj, xb, wqb, wkb, wvb, wpb);
    gemm_qkv<<<dim3(8, 64, 3), 256, 0, stream>>>(xb, wqb, wkb, wvb, qo, ko, vt);
    rope_rms2<<<dim3(8192, 2), 256, 0, stream>>>(qo, ko);
    diff_attn2<<<dim3(32, 32), 256, 0, stream>>>(qo, ko, vt, lq1, lk1, lq2, lk2, a);
    gemm_proj<<<dim3(8, 64), 256, 0, stream>>>(a, wpb, O);
  } else {
    // ---------- FALLBACK (round-4 proven, zero ws) ----------
    char* Ob = (char*)d_out;
    char* Xb = (char*)d_in[0];
    const size_t MB4 = (size_t)1 << 22;
    bf16_t* qb[4] = { (bf16_t*)(Ob + 2*MB4), (bf16_t*)(Ob + 5*MB4),
                      (bf16_t*)(Xb + 0*MB4), (bf16_t*)(Xb + 3*MB4) };
    bf16_t* kb[4] = { (bf16_t*)(Ob + 3*MB4), (bf16_t*)(Ob + 6*MB4),
                      (bf16_t*)(Xb + 1*MB4), (bf16_t*)(Xb + 4*MB4) };
    bf16_t* vb[4] = { (bf16_t*)(Ob + 4*MB4), (bf16_t*)(Ob + 7*MB4),
                      (bf16_t*)(Xb + 2*MB4), (bf16_t*)(Xb + 5*MB4) };
    for (int b = 0; b < 4; ++b) {
      const float* xbp = x + (size_t)b * R;
      gemm_bt<true, false><<<dim3(8, 16, 3), 256, 0, stream>>>(
          xbp, Wq, Wk, Wv, qb[b], kb[b], vb[b]);
      rope_rms<<<2048, 256, 0, stream>>>(qb[b], 1);
      rope_rms<<<2048, 256, 0, stream>>>(kb[b], 0);
      diff_attn<<<dim3(32, 8), 256, 0, stream>>>(qb[b], kb[b], vb[b],
                                                 lq1, lk1, lq2, lk2, qb[b]);
      gemm_bt<false, true><<<dim3(8, 16, 1), 256, 0, stream>>>(
          qb[b], Wproj, Wproj, Wproj, O + (size_t)b * R, nullptr, nullptr);
    }
  }
}